// Round 7
// baseline (229.216 us; speedup 1.0000x reference)
//
#include <hip/hip_runtime.h>

#define NSEG 511
#define NROWS 8            // rows 8..15 only
#define ROW0 8
#define K0 21              // first needed freq bin
#define KEND 500           // bins k with 20 < k < 500
#define NFREQ 479
#define ACC_STRIDE 512     // padded per-row accumulator stride
#define ACC_ELEMS (2 * NROWS * ACC_STRIDE)   // one replica
#define NREP 8             // accumulator replicas
#define SPB 8              // segments per block (8 -> 1024 blocks = 4/CU)
#define NGROUPS 64         // ceil(511/8)
#define NBLOCKS (2 * NROWS * NGROUPS)        // 1024

// XOR swizzle for the FFT buffer (stages A/B/C exchange).
__device__ __forceinline__ int sw(int i) { return i ^ (((i >> 5) & 7) << 2); }
// Natural-order bin map, per r-plane: nsw(m) = m ^ (((m>>4)&3)<<2).
// BIJECTIVE on [0,512); full address 512*r + (nsw(m)^r) makes stage-C scatter
// writes land exactly 4 lanes/bank-pair (b64 minimum) and untangle reads
// uniform. Preserves +64p / +-256 immediate-offset structure.
__device__ __forceinline__ int nsw(int m) { return m ^ (((m >> 4) & 3) << 2); }

__device__ __forceinline__ float2 cmul(float2 a, float2 b) {
    return make_float2(fmaf(a.x, b.x, -a.y * b.y), fmaf(a.x, b.y, a.y * b.x));
}
__device__ __forceinline__ float2 cadd(float2 a, float2 b) { return make_float2(a.x + b.x, a.y + b.y); }
__device__ __forceinline__ float2 csub(float2 a, float2 b) { return make_float2(a.x - b.x, a.y - b.y); }

// In-register 8-point DFT (DIF).
__device__ __forceinline__ void dft8(float2& x0, float2& x1, float2& x2, float2& x3,
                                     float2& x4, float2& x5, float2& x6, float2& x7) {
    const float C45 = 0.70710678118654752440f;
    float2 t0 = cadd(x0, x4), u0 = csub(x0, x4);
    float2 t1 = cadd(x1, x5), u1 = csub(x1, x5);
    float2 t2 = cadd(x2, x6), u2 = csub(x2, x6);
    float2 t3 = cadd(x3, x7), u3 = csub(x3, x7);
    float2 s0 = cadd(t0, t2), d0 = csub(t0, t2);
    float2 s1 = cadd(t1, t3), d1 = csub(t1, t3);
    float2 v1 = make_float2(C45 * (u1.x + u1.y), C45 * (u1.y - u1.x));
    float2 v2 = make_float2(u2.y, -u2.x);
    float2 v3 = make_float2(C45 * (u3.y - u3.x), -C45 * (u3.x + u3.y));
    float2 s2 = cadd(u0, v2), d2 = csub(u0, v2);
    float2 s3 = cadd(v1, v3), d3 = csub(v1, v3);
    float2 mid1 = make_float2(d1.y, -d1.x);   // -i * d1
    float2 mid3 = make_float2(d3.y, -d3.x);   // -i * d3
    x0 = cadd(s0, s1); x4 = csub(s0, s1);
    x2 = cadd(d0, mid1); x6 = csub(d0, mid1);
    x1 = cadd(s2, s3); x5 = csub(s2, s3);
    x3 = cadd(d2, mid3); x7 = csub(d2, mid3);
}

// Build w^1..w^7 from w = (c,s). Hoisted pre-loop (segment-invariant).
__device__ __forceinline__ void twbuild(float c, float s,
                                        float2& w1, float2& w2, float2& w3, float2& w4,
                                        float2& w5, float2& w6, float2& w7) {
    w1 = make_float2(c, s);
    w2 = cmul(w1, w1);
    w3 = cmul(w2, w1);
    w4 = cmul(w2, w2);
    w5 = cmul(w4, w1);
    w6 = cmul(w3, w3);
    w7 = cmul(w4, w3);
}
// Apply precomputed twiddles.
__device__ __forceinline__ void twapply(float2& x1, float2& x2, float2& x3, float2& x4,
                                        float2& x5, float2& x6, float2& x7,
                                        float2 w1, float2 w2, float2 w3, float2 w4,
                                        float2 w5, float2 w6, float2 w7) {
    x1 = cmul(x1, w1); x2 = cmul(x2, w2); x3 = cmul(x3, w3);
    x4 = cmul(x4, w4); x5 = cmul(x5, w5); x6 = cmul(x6, w6);
    x7 = cmul(x7, w7);
}

// FFT body identical to round 5 (passing, 49.7-51 us). New: the reduce is
// fused via the LAST-BLOCK pattern (graph-capture-safe, unlike cooperative
// launch which failed silently in round 6: unwritten out -> absmax == |ref|):
//   every block: atomic flush -> __threadfence (release) -> ticket atomicAdd;
//   the block drawing ticket NBLOCKS-1: __threadfence (acquire) -> 256-thread
//   ratio reduction over acc -> out[0]. acc AND ticket are zeroed by the
//   stream-ordered hipMemsetAsync before the dispatch; no grid sync needed,
//   no residency or dispatch-order assumption.
// NOTE: __launch_bounds__(256) ONLY — forcing min-waves made the allocator
// spill (round 1: VGPR 40, 165 MB scratch, 3x regression).
__global__ __launch_bounds__(256)
void psd_kernel(const float* __restrict__ pred,
                const float* __restrict__ target,
                float* __restrict__ acc,
                unsigned int* __restrict__ ticket,
                float* __restrict__ out) {
    __shared__ float2 buf[2048];   // 16 KiB FFT workspace (reused by reduce)
    __shared__ float2 nat[2048];   // 16 KiB natural-order planes (4 x 512, XOR map)
    __shared__ int isLast;

    const int bid = blockIdx.x;
    const int grp = bid % NGROUPS;
    const int row = (bid / NGROUPS) % NROWS + ROW0;
    const int sig = bid / (NGROUPS * NROWS);   // 0 = res (target-pred), 1 = target
    const int tid = threadIdx.x;
    const int seg0 = grp * SPB;
    const int ns = (seg0 + SPB <= NSEG) ? SPB : (NSEG - seg0);   // 8 (last group: 7)

    const float2* t2p = (const float2*)target;
    const float2* p2p = (const float2*)pred;

    // Complex point m of segment s: real samples at batch row 2(seg0+s)+(m>>9),
    // float2 offset row*512 + (m&511). m = tid + 256*R.
    const int base = 2 * seg0 * 8192 + row * 512 + tid;
#define LOADRAW(X, IDX)                                                      \
    {                                                                        \
        int _i = (IDX);                                                      \
        float2 v = t2p[_i];                                                  \
        if (sig == 0) { float2 p = p2p[_i]; v.x -= p.x; v.y -= p.y; }        \
        X = v;                                                               \
    }
    float2 r0, r1, r2, r3, r4, r5, r6, r7;
    LOADRAW(r0, base)
    LOADRAW(r1, base + 256)
    LOADRAW(r2, base + 8192)
    LOADRAW(r3, base + 8448)
    LOADRAW(r4, base + 16384)
    LOADRAW(r5, base + 16640)
    LOADRAW(r6, base + 24576)
    LOADRAW(r7, base + 24832)

    // ---- hoisted trig + twiddles (segment-invariant; overlaps load latency) ----
    const float WA = 3.06796157577128245e-3f;      // 2*pi/2048
    const float CD = 0.99999882344642529f;         // cos(pi/2048)
    const float SD = 1.53398018628476550e-3f;      // sin(pi/2048)
    const float H  = 0.70710678118654752440f;      // sqrt(2)/2
    float sa, ca;
    __sincosf((float)tid * WA, &sa, &ca);          // window base; stage-A tw = (ca,-sa)
    // window weights per R (rotations of (ca,sa) by R*pi/4), w = (even, odd)
    float2 wv0, wv1, wv2, wv3, wv4, wv5, wv6, wv7;
#define MKW(W, CE, SE) { float cr = (CE), sr = (SE);                         \
        W = make_float2(1.0f - cr, 1.0f - (cr * CD - sr * SD)); }
    MKW(wv0, ca, sa)
    MKW(wv1, H * (ca - sa), H * (sa + ca))
    MKW(wv2, -sa, ca)
    MKW(wv3, -H * (ca + sa), H * (ca - sa))
    MKW(wv4, -ca, -sa)
    MKW(wv5, H * (sa - ca), -H * (sa + ca))
    MKW(wv6, sa, -ca)
    MKW(wv7, H * (ca + sa), H * (sa - ca))
#undef MKW
    // stage-A twiddle chain (base (ca,-sa))
    float2 wA1, wA2, wA3, wA4, wA5, wA6, wA7;
    twbuild(ca, -sa, wA1, wA2, wA3, wA4, wA5, wA6, wA7);
    // stage-B twiddle chain (depends on tid&31 only)
    {
        float sb, cb;
        __sincosf((float)(tid & 31) * -2.45436926061702596e-2f, &sb, &cb);  // -2*pi/256
        sa = sb; ca = cb;   // reuse regs
    }
    float2 wB1, wB2, wB3, wB4, wB5, wB6, wB7;
    twbuild(ca, sa, wB1, wB2, wB3, wB4, wB5, wB6, wB7);
    // stage-C twiddle base (depends on tid&3 only): constants
    float cc, ss;
    {
        const float TC1 = 0.98078528040323044913f, TS1 = -0.19509032201612826785f;
        const float TC2 = 0.92387953251128675613f, TS2 = -0.38268343236508977173f;
        const float TC3 = 0.83146961230254523708f, TS3 = -0.55557023301960222474f;
        int mq = tid & 3;
        cc = (mq & 2) ? ((mq & 1) ? TC3 : TC2) : ((mq & 1) ? TC1 : 1.0f);
        ss = (mq & 2) ? ((mq & 1) ? TS3 : TS2) : ((mq & 1) ? TS1 : 0.0f);
    }
    float2 wC1, wC2, wC3, wC4, wC5, wC6, wC7;
    twbuild(cc, ss, wC1, wC2, wC3, wC4, wC5, wC6, wC7);

    const int k1 = K0 + tid;                       // 21..276, always < 500
    const bool has2 = (tid < KEND - K0 - 256);     // k2 = k1+256 < 500, k1 <= 243

    // untangle twiddles for bins k1 and k2 = k1+256 (-pi/8 rotation)
    float sn0, cs0, sn1, cs1;
    __sincosf(-1.53398078788564123e-3f * (float)k1, &sn0, &cs0);  // -2*pi*k/4096
    {
        const float CU = 0.98078528040323044913f;   // cos(pi/8)
        const float SU = 0.19509032201612826785f;   // sin(pi/8)
        cs1 = cs0 * CU + sn0 * SU;
        sn1 = sn0 * CU - cs0 * SU;
    }

    // Natural-plane base addresses (segment-invariant). Bin k needs slot r
    // values of quad m=k (X0 -> Z[k]) and m=512-k (X3 -> Z[2048-k]) at
    // 512r + (nsw(m)^r). k2 = k1+256 variants are +/-256 immediate offsets.
    const int qk0 = nsw(k1);
    const int qn0 = nsw(512 - k1);

    // Stage-C scatter base: bin m = 64p + mb, slot r = tid&3.
    const int mb = 8 * ((tid >> 2) & 7) + (tid >> 5);
    const int natC = (nsw(mb) ^ (tid & 3)) + 512 * (tid & 3);

    float pw1 = 0.0f, pw2 = 0.0f;   // register power accumulators (2 bins/thread)

    // ---- prologue: stage A for segment 0 ----
    {
        float2 x0 = make_float2(r0.x * wv0.x, r0.y * wv0.y);
        float2 x1 = make_float2(r1.x * wv1.x, r1.y * wv1.y);
        float2 x2 = make_float2(r2.x * wv2.x, r2.y * wv2.y);
        float2 x3 = make_float2(r3.x * wv3.x, r3.y * wv3.y);
        float2 x4 = make_float2(r4.x * wv4.x, r4.y * wv4.y);
        float2 x5 = make_float2(r5.x * wv5.x, r5.y * wv5.y);
        float2 x6 = make_float2(r6.x * wv6.x, r6.y * wv6.y);
        float2 x7 = make_float2(r7.x * wv7.x, r7.y * wv7.y);
        if (ns > 1) {   // prefetch segment 1's new half
            r0 = r4; r1 = r5; r2 = r6; r3 = r7;
            int nb = base + 16384;
            LOADRAW(r4, nb + 16384)
            LOADRAW(r5, nb + 16640)
            LOADRAW(r6, nb + 24576)
            LOADRAW(r7, nb + 24832)
        }
        dft8(x0, x1, x2, x3, x4, x5, x6, x7);
        twapply(x1, x2, x3, x4, x5, x6, x7, wA1, wA2, wA3, wA4, wA5, wA6, wA7);
        buf[sw(tid)]        = x0;
        buf[sw(tid + 256)]  = x1;
        buf[sw(tid + 512)]  = x2;
        buf[sw(tid + 768)]  = x3;
        buf[sw(tid + 1024)] = x4;
        buf[sw(tid + 1280)] = x5;
        buf[sw(tid + 1536)] = x6;
        buf[sw(tid + 1792)] = x7;
    }
    __syncthreads();

    #pragma unroll 1
    for (int s = 0; s < ns; ++s) {
        // ---- stage B: radix-8 stride 32 within each 256-subFFT
        {
            const int baseB = (tid & 31) + 256 * (tid >> 5);
            float2 x0 = buf[sw(baseB)];
            float2 x1 = buf[sw(baseB + 32)];
            float2 x2 = buf[sw(baseB + 64)];
            float2 x3 = buf[sw(baseB + 96)];
            float2 x4 = buf[sw(baseB + 128)];
            float2 x5 = buf[sw(baseB + 160)];
            float2 x6 = buf[sw(baseB + 192)];
            float2 x7 = buf[sw(baseB + 224)];
            dft8(x0, x1, x2, x3, x4, x5, x6, x7);
            twapply(x1, x2, x3, x4, x5, x6, x7, wB1, wB2, wB3, wB4, wB5, wB6, wB7);
            buf[sw(baseB)]       = x0;
            buf[sw(baseB + 32)]  = x1;
            buf[sw(baseB + 64)]  = x2;
            buf[sw(baseB + 96)]  = x3;
            buf[sw(baseB + 128)] = x4;
            buf[sw(baseB + 160)] = x5;
            buf[sw(baseB + 192)] = x6;
            buf[sw(baseB + 224)] = x7;
        }
        // NO barrier: B->C data flow is intra-wave (32-block t>>5 belongs to
        // wave t>>6 on both sides; lgkmcnt ordering suffices within a wave)

        // ---- stage C: radix-8 stride 4; outputs scattered straight into
        // natural bin order (fused digit reversal), conflict-free via nsw^r.
        {
            const int baseC = (tid & 3) + 32 * ((tid >> 2) & 7) + 256 * (tid >> 5);
            float2 x0 = buf[sw(baseC)];
            float2 x1 = buf[sw(baseC + 4)];
            float2 x2 = buf[sw(baseC + 8)];
            float2 x3 = buf[sw(baseC + 12)];
            float2 x4 = buf[sw(baseC + 16)];
            float2 x5 = buf[sw(baseC + 20)];
            float2 x6 = buf[sw(baseC + 24)];
            float2 x7 = buf[sw(baseC + 28)];
            dft8(x0, x1, x2, x3, x4, x5, x6, x7);
            twapply(x1, x2, x3, x4, x5, x6, x7, wC1, wC2, wC3, wC4, wC5, wC6, wC7);
            nat[natC]       = x0;
            nat[natC + 64]  = x1;
            nat[natC + 128] = x2;
            nat[natC + 192] = x3;
            nat[natC + 256] = x4;
            nat[natC + 320] = x5;
            nat[natC + 384] = x6;
            nat[natC + 448] = x7;
        }
        __syncthreads();   // C-writes -> untangle-reads; C-buf-reads -> A-writes

        // ---- stage A for segment s+1 (same window as untangle: A's VALU
        // overlaps untangle's LDS reads; buf/nat disjoint)
        if (s + 1 < ns) {
            float2 x0 = make_float2(r0.x * wv0.x, r0.y * wv0.y);
            float2 x1 = make_float2(r1.x * wv1.x, r1.y * wv1.y);
            float2 x2 = make_float2(r2.x * wv2.x, r2.y * wv2.y);
            float2 x3 = make_float2(r3.x * wv3.x, r3.y * wv3.y);
            float2 x4 = make_float2(r4.x * wv4.x, r4.y * wv4.y);
            float2 x5 = make_float2(r5.x * wv5.x, r5.y * wv5.y);
            float2 x6 = make_float2(r6.x * wv6.x, r6.y * wv6.y);
            float2 x7 = make_float2(r7.x * wv7.x, r7.y * wv7.y);
            if (s + 2 < ns) {   // prefetch segment s+2's new half
                r0 = r4; r1 = r5; r2 = r6; r3 = r7;
                int nb = base + (s + 2) * 16384;
                LOADRAW(r4, nb + 16384)
                LOADRAW(r5, nb + 16640)
                LOADRAW(r6, nb + 24576)
                LOADRAW(r7, nb + 24832)
            }
            dft8(x0, x1, x2, x3, x4, x5, x6, x7);
            twapply(x1, x2, x3, x4, x5, x6, x7, wA1, wA2, wA3, wA4, wA5, wA6, wA7);
            buf[sw(tid)]        = x0;
            buf[sw(tid + 256)]  = x1;
            buf[sw(tid + 512)]  = x2;
            buf[sw(tid + 768)]  = x3;
            buf[sw(tid + 1024)] = x4;
            buf[sw(tid + 1280)] = x5;
            buf[sw(tid + 1536)] = x6;
            buf[sw(tid + 1792)] = x7;
        }

        // ---- fused radix-4 + untangle from natural planes:
        // X0(m) = v0+v1+v2+v3 ; X3(m) = (v0-v2) - i*(v1-v3).
        // zk = X0(k) = Z[k], zn = X3(512-k) = Z[2048-k].
        {
            float2 a0 = nat[qk0];
            float2 a1 = nat[(qk0 ^ 1) + 512];
            float2 a2 = nat[(qk0 ^ 2) + 1024];
            float2 a3 = nat[(qk0 ^ 3) + 1536];
            float2 zk = make_float2((a0.x + a1.x) + (a2.x + a3.x),
                                    (a0.y + a1.y) + (a2.y + a3.y));
            float2 b0 = nat[qn0];
            float2 b1 = nat[(qn0 ^ 1) + 512];
            float2 b2 = nat[(qn0 ^ 2) + 1024];
            float2 b3 = nat[(qn0 ^ 3) + 1536];
            float D0x = b0.x - b2.x, D0y = b0.y - b2.y;
            float D1x = b1.x - b3.x, D1y = b1.y - b3.y;
            float2 zn = make_float2(D0x - D1y, D0y + D1x);
            float Ex = 0.5f * (zk.x + zn.x);
            float Ey = 0.5f * (zk.y - zn.y);
            float Ox = 0.5f * (zk.y + zn.y);
            float Oy = -0.5f * (zk.x - zn.x);
            float xr = Ex + Ox * cs0 - Oy * sn0;
            float xi = Ey + Ox * sn0 + Oy * cs0;
            pw1 += xr * xr + xi * xi;
        }
        if (has2) {
            float2 a0 = nat[qk0 + 256];
            float2 a1 = nat[(qk0 ^ 1) + 768];
            float2 a2 = nat[(qk0 ^ 2) + 1280];
            float2 a3 = nat[(qk0 ^ 3) + 1792];
            float2 zk = make_float2((a0.x + a1.x) + (a2.x + a3.x),
                                    (a0.y + a1.y) + (a2.y + a3.y));
            float2 b0 = nat[qn0 - 256];
            float2 b1 = nat[(qn0 ^ 1) + 256];
            float2 b2 = nat[(qn0 ^ 2) + 768];
            float2 b3 = nat[(qn0 ^ 3) + 1280];
            float D0x = b0.x - b2.x, D0y = b0.y - b2.y;
            float D1x = b1.x - b3.x, D1y = b1.y - b3.y;
            float2 zn = make_float2(D0x - D1y, D0y + D1x);
            float Ex = 0.5f * (zk.x + zn.x);
            float Ey = 0.5f * (zk.y - zn.y);
            float Ox = 0.5f * (zk.y + zn.y);
            float Oy = -0.5f * (zk.x - zn.x);
            float xr = Ex + Ox * cs1 - Oy * sn1;
            float xi = Ey + Ox * sn1 + Oy * cs1;
            pw2 += xr * xr + xi * xi;
        }
        if (s + 1 < ns) __syncthreads();   // A-writes -> B-reads; untangle -> C(s+1)
    }

    // ---- single atomic flush per thread ----
    {
        float* accR = acc + (bid & (NREP - 1)) * ACC_ELEMS;
        int i0 = (sig * NROWS + (row - ROW0)) * ACC_STRIDE;
        atomicAdd(&accR[i0 + tid], pw1);
        if (has2) atomicAdd(&accR[i0 + 256 + tid], pw2);
    }
#undef LOADRAW

    // ---- last-block reduction (graph-capture-safe fusion of reduce_kernel):
    // release: make this block's atomics visible, then draw a ticket.
    __threadfence();
    __syncthreads();
    if (tid == 0) {
        unsigned int t = atomicAdd(ticket, 1u);
        isLast = (t == NBLOCKS - 1);
    }
    __syncthreads();
    if (isLast) {
        __threadfence();   // acquire: see all blocks' flushed atomics
        // out = sum over (row,k) of P_res/P_tgt, / 240.
        // (dfreq=1, scale=480, mean(last 8)*16 => 2/480 = 1/240; /T cancels)
        float* sh = (float*)buf;   // reuse FFT workspace as reduction scratch
        float sum = 0.0f;
        for (int n = tid; n < NROWS * NFREQ; n += 256) {
            int r = n / NFREQ, k = n % NFREQ;
            float num = 0.0f, den = 0.0f;
            #pragma unroll
            for (int rep = 0; rep < NREP; ++rep) {
                num += acc[rep * ACC_ELEMS + r * ACC_STRIDE + k];
                den += acc[rep * ACC_ELEMS + (NROWS + r) * ACC_STRIDE + k];
            }
            sum += num / den;
        }
        sh[tid] = sum;
        __syncthreads();
        for (int s2 = 128; s2 > 0; s2 >>= 1) {
            if (tid < s2) sh[tid] += sh[tid + s2];
            __syncthreads();
        }
        if (tid == 0) out[0] = sh[0] * (1.0f / 240.0f);
    }
}

extern "C" void kernel_launch(void* const* d_in, const int* in_sizes, int n_in,
                              void* d_out, int out_size, void* d_ws, size_t ws_size,
                              hipStream_t stream) {
    const float* pred = (const float*)d_in[0];
    const float* target = (const float*)d_in[1];
    float* acc = (float*)d_ws;        // NREP replicas of [2][NROWS][ACC_STRIDE] = 256 KiB
    unsigned int* ticket = (unsigned int*)((char*)d_ws + NREP * ACC_ELEMS * sizeof(float));

    // zero acc + ticket in one stream-ordered memset (ordering before the
    // kernel's atomics is guaranteed by stream order; no grid sync needed)
    hipMemsetAsync(acc, 0, NREP * ACC_ELEMS * sizeof(float) + 16, stream);
    psd_kernel<<<NBLOCKS, 256, 0, stream>>>(pred, target, acc, ticket, (float*)d_out);
}